// Round 2
// 1155.510 us; speedup vs baseline: 1.6153x; 1.6153x over previous
//
#include <hip/hip_runtime.h>
#include <hip/hip_bf16.h>

#define H_ 12
#define D_ 64
#define S_ 2048
#define B_ 2
#define HID_ 768

typedef short bf8 __attribute__((ext_vector_type(8)));
typedef float f4 __attribute__((ext_vector_type(4)));

#define MFMA(a,b,c) __builtin_amdgcn_mfma_f32_16x16x32_bf16(a,b,c,0,0,0)

__device__ __forceinline__ unsigned short f2bf(float f){
  __hip_bfloat16 h = __float2bfloat16(f);
  return __builtin_bit_cast(unsigned short, h);
}

__device__ __forceinline__ void st4bf(unsigned short* dst, float4 v){
  unsigned int u0 = (unsigned int)f2bf(v.x) | ((unsigned int)f2bf(v.y) << 16);
  unsigned int u1 = (unsigned int)f2bf(v.z) | ((unsigned int)f2bf(v.w) << 16);
  uint2 u; u.x = u0; u.y = u1;
  *reinterpret_cast<uint2*>(dst) = u;
}

// ---------------- QKV projection: y = x @ W^T + b, routed to bf16 buffers ----
// q,k -> [B,H,S,D]; v -> transposed [B,H,D,S]
__global__ __launch_bounds__(256) void proj_kernel(
    const float* __restrict__ Xq, const float* __restrict__ Xk, const float* __restrict__ Xv,
    const float* __restrict__ Wq_, const float* __restrict__ Wk_, const float* __restrict__ Wv_,
    const float* __restrict__ bq_, const float* __restrict__ bk_, const float* __restrict__ bv_,
    unsigned short* __restrict__ qb, unsigned short* __restrict__ kb,
    unsigned short* __restrict__ vtb)
{
  const int sel = blockIdx.z;
  const float* X    = sel==0 ? Xq  : (sel==1 ? Xk  : Xv);
  const float* W    = sel==0 ? Wq_ : (sel==1 ? Wk_ : Wv_);
  const float* bias = sel==0 ? bq_ : (sel==1 ? bk_ : bv_);
  const int m0 = blockIdx.x*64, n0 = blockIdx.y*64;
  __shared__ unsigned short lA[64*72];  // +8 pad: bank-friendly, keeps 16B align
  __shared__ unsigned short lB[64*72];
  const int tid = threadIdx.x;
  const int lane = tid & 63, w = tid >> 6;
  const int quad = lane >> 4, l16 = lane & 15;
  const int wm = (w>>1)*32, wn = (w&1)*32;
  f4 acc[2][2] = {};
  for (int k0=0; k0<HID_; k0+=64){
    #pragma unroll
    for (int i=0;i<4;i++){
      int idx = tid + i*256;               // 0..1023
      int r = idx>>4, c4 = idx&15;         // 64 rows x 16 float4
      float4 va = *reinterpret_cast<const float4*>(&X[(size_t)(m0+r)*HID_ + k0 + c4*4]);
      st4bf(&lA[r*72 + c4*4], va);
      float4 vb = *reinterpret_cast<const float4*>(&W[(size_t)(n0+r)*HID_ + k0 + c4*4]);
      st4bf(&lB[r*72 + c4*4], vb);
    }
    __syncthreads();
    #pragma unroll
    for (int kc=0;kc<2;kc++){
      bf8 a0 = *reinterpret_cast<const bf8*>(&lA[(wm    + l16)*72 + kc*32 + quad*8]);
      bf8 a1 = *reinterpret_cast<const bf8*>(&lA[(wm+16 + l16)*72 + kc*32 + quad*8]);
      bf8 b0 = *reinterpret_cast<const bf8*>(&lB[(wn    + l16)*72 + kc*32 + quad*8]);
      bf8 b1 = *reinterpret_cast<const bf8*>(&lB[(wn+16 + l16)*72 + kc*32 + quad*8]);
      acc[0][0] = MFMA(a0,b0,acc[0][0]);
      acc[0][1] = MFMA(a0,b1,acc[0][1]);
      acc[1][0] = MFMA(a1,b0,acc[1][0]);
      acc[1][1] = MFMA(a1,b1,acc[1][1]);
    }
    __syncthreads();
  }
  #pragma unroll
  for (int i=0;i<2;i++)
    #pragma unroll
    for (int j=0;j<2;j++)
      #pragma unroll
      for (int reg=0;reg<4;reg++){
        int row = m0 + wm + i*16 + quad*4 + reg;     // b*S+s
        int col = n0 + wn + j*16 + l16;              // h*64+d
        float val = acc[i][j][reg] + bias[col];
        int bb = row >> 11, s = row & 2047;
        int hh = col >> 6,  d = col & 63;
        unsigned short bv16 = f2bf(val);
        if (sel==0)      qb [((size_t)(bb*H_+hh)*S_ + s)*D_ + d] = bv16;
        else if (sel==1) kb [((size_t)(bb*H_+hh)*S_ + s)*D_ + d] = bv16;
        else             vtb[((size_t)(bb*H_+hh)*D_ + d)*S_ + s] = bv16;
      }
}

// ---------------- fused attention: scores + prev_attn_out + online softmax + PV
// Swapped-operand QK^T: scores held TRANSPOSED per lane (col=l16 -> fixed q row,
// quad*4+reg -> 4 contiguous k cols). pb/mask/prev/prev_out become float4 ops.
// K/V fragments read direct from global (L2-resident); LDS only holds per-wave
// private P strips -> zero __syncthreads() in the whole kernel.
__global__ __launch_bounds__(256) void attn_kernel(
  const unsigned short* __restrict__ qb, const unsigned short* __restrict__ kb,
  const unsigned short* __restrict__ vtb,
  const float* __restrict__ pb, const float* __restrict__ msk,
  const float* __restrict__ prev, const int* __restrict__ flagp,
  float* __restrict__ prev_out, unsigned short* __restrict__ ctxb)
{
  const int qt = blockIdx.x, hh = blockIdx.y, bb = blockIdx.z;
  const int tid = threadIdx.x, w = tid>>6, lane = tid&63;
  const int quad = lane>>4, l16 = lane&15;
  const int flag = *flagp;
  __shared__ unsigned short lP[4*16*136];   // per-wave [16 q][128 k] strips, pad 136
  const int pbase = w*16*136;
  const unsigned short* Kb = kb  + (size_t)(bb*H_+hh)*S_*D_;
  const unsigned short* Vb = vtb + (size_t)(bb*H_+hh)*D_*S_;
  const unsigned short* Qb = qb  + (size_t)(bb*H_+hh)*S_*D_;
  const int q0 = qt*64;
  const int qq = q0 + w*16 + l16;           // this lane's q row
  // Q fragment (B-operand): lane supplies Q[q0+w*16+l16][quad*8 + e]
  bf8 qf0 = *reinterpret_cast<const bf8*>(&Qb[(size_t)qq*D_ + quad*8]);
  bf8 qf1 = *reinterpret_cast<const bf8*>(&Qb[(size_t)qq*D_ + 32 + quad*8]);
  const float* pbB = pb   + (size_t)hh*S_*S_;
  const float* mkB = msk  + (size_t)bb*S_*S_;
  const float* pvB = prev + (size_t)(bb*H_+hh)*S_*S_;
  float*       poB = prev_out + (size_t)(bb*H_+hh)*S_*S_;

  float m_run = -1e30f, l_run = 0.f;
  f4 O[4] = {};                             // O^T: d = n*16+quad*4+reg, q = l16

  for (int kt=0; kt<S_; kt+=128){
    f4 sc[8];
    float mt = -1e30f;
    #pragma unroll
    for (int half=0; half<2; half++){
      // issue bias/mask/prev loads first (independent of K), then K frags + MFMA
      f4 pbv[4], mkv[4], pvv[4];
      #pragma unroll
      for (int cc=0; cc<4; cc++){
        int c = half*4+cc;
        size_t off = (size_t)qq*S_ + kt + c*16 + quad*4;
        pbv[cc] = *reinterpret_cast<const f4*>(&pbB[off]);
        mkv[cc] = *reinterpret_cast<const f4*>(&mkB[off]);
      }
      if (flag){
        #pragma unroll
        for (int cc=0; cc<4; cc++){
          int c = half*4+cc;
          size_t off = (size_t)qq*S_ + kt + c*16 + quad*4;
          pvv[cc] = *reinterpret_cast<const f4*>(&pvB[off]);
        }
      } else {
        #pragma unroll
        for (int cc=0; cc<4; cc++){ pvv[cc][0]=0.f; pvv[cc][1]=0.f; pvv[cc][2]=0.f; pvv[cc][3]=0.f; }
      }
      // S^T = K Q^T : A = K fragment (row = k), B = Q fragment (col = q)
      #pragma unroll
      for (int cc=0; cc<4; cc++){
        int c = half*4+cc;
        const unsigned short* kr = &Kb[(size_t)(kt + c*16 + l16)*D_ + quad*8];
        bf8 k0v = *reinterpret_cast<const bf8*>(kr);
        bf8 k1v = *reinterpret_cast<const bf8*>(kr + 32);
        f4 z = {};
        z = MFMA(k0v, qf0, z);
        z = MFMA(k1v, qf1, z);
        sc[c] = z;
      }
      // assemble scores (4 contiguous k per lane -> float4), write prev_attn_out
      #pragma unroll
      for (int cc=0; cc<4; cc++){
        int c = half*4+cc;
        size_t off = (size_t)qq*S_ + kt + c*16 + quad*4;
        f4 vout;
        #pragma unroll
        for (int reg=0; reg<4; reg++){
          float v = (sc[c][reg] + pbv[cc][reg])*0.125f + mkv[cc][reg] + pvv[cc][reg];
          vout[reg] = v;
          mt = fmaxf(mt, v);
        }
        *reinterpret_cast<f4*>(&poB[off]) = vout;
        sc[c] = vout;
      }
    }
    // online softmax: per-lane scalar state (one q row per lane),
    // cross-quad reduce covers all 128 k of this tile
    mt = fmaxf(mt, __shfl_xor(mt, 16, 64));
    mt = fmaxf(mt, __shfl_xor(mt, 32, 64));
    float mn = fmaxf(m_run, mt);
    float al = __expf(m_run - mn);
    m_run = mn;
    float ps = 0.f;
    #pragma unroll
    for (int c=0;c<8;c++)
      #pragma unroll
      for (int reg=0;reg<4;reg++){
        float p = __expf(sc[c][reg] - mn);
        sc[c][reg] = p;
        ps += p;
      }
    ps += __shfl_xor(ps, 16, 64);
    ps += __shfl_xor(ps, 32, 64);
    l_run = l_run*al + ps;
    #pragma unroll
    for (int n=0;n<4;n++)
      #pragma unroll
      for (int reg=0;reg<4;reg++) O[n][reg] *= al;
    // P -> per-wave LDS strip, layout [q=l16][k], 8B packed stores
    #pragma unroll
    for (int c=0;c<8;c++){
      unsigned int u0 = (unsigned int)f2bf(sc[c][0]) | ((unsigned int)f2bf(sc[c][1])<<16);
      unsigned int u1 = (unsigned int)f2bf(sc[c][2]) | ((unsigned int)f2bf(sc[c][3])<<16);
      uint2 u; u.x=u0; u.y=u1;
      *reinterpret_cast<uint2*>(&lP[pbase + l16*136 + c*16 + quad*4]) = u;
    }
    // O^T += Vt P^T : A = Vt fragment (direct global, row = d), B = P fragment
    #pragma unroll
    for (int kb_=0;kb_<4;kb_++){
      bf8 pa = *reinterpret_cast<const bf8*>(&lP[pbase + l16*136 + kb_*32 + quad*8]);
      #pragma unroll
      for (int n=0;n<4;n++){
        bf8 vv = *reinterpret_cast<const bf8*>(&Vb[(size_t)(n*16+l16)*S_ + kt + kb_*32 + quad*8]);
        O[n] = MFMA(vv, pa, O[n]);
      }
    }
  }
  // epilogue: ctx = O^T / l, store bf16 [B,S,H*D]; 4 contiguous d per n -> 8B stores
  float rcp = 1.f / l_run;
  #pragma unroll
  for (int n=0;n<4;n++){
    unsigned int u0 = (unsigned int)f2bf(O[n][0]*rcp) | ((unsigned int)f2bf(O[n][1]*rcp)<<16);
    unsigned int u1 = (unsigned int)f2bf(O[n][2]*rcp) | ((unsigned int)f2bf(O[n][3]*rcp)<<16);
    uint2 u; u.x=u0; u.y=u1;
    *reinterpret_cast<uint2*>(&ctxb[(size_t)(bb*S_+qq)*HID_ + hh*D_ + n*16 + quad*4]) = u;
  }
}

// ---------------- output projection: out = ctx @ Wo^T + bo (fp32 out) --------
__global__ __launch_bounds__(256) void outproj_kernel(
  const unsigned short* __restrict__ ctxb, const float* __restrict__ Wo,
  const float* __restrict__ bo, float* __restrict__ out)
{
  const int m0 = blockIdx.x*64, n0 = blockIdx.y*64;
  __shared__ unsigned short lA[64*72];
  __shared__ unsigned short lB[64*72];
  const int tid = threadIdx.x;
  const int lane = tid&63, w = tid>>6;
  const int quad = lane>>4, l16 = lane&15;
  const int wm = (w>>1)*32, wn = (w&1)*32;
  f4 acc[2][2] = {};
  for (int k0=0;k0<HID_;k0+=64){
    #pragma unroll
    for (int i=0;i<2;i++){
      int idx = tid + i*256;                // 0..511
      int r = idx>>3, c8 = idx&7;
      *reinterpret_cast<uint4*>(&lA[r*72 + c8*8]) =
        *reinterpret_cast<const uint4*>(&ctxb[(size_t)(m0+r)*HID_ + k0 + c8*8]);
    }
    #pragma unroll
    for (int i=0;i<4;i++){
      int idx = tid + i*256;
      int r = idx>>4, c4 = idx&15;
      float4 vb = *reinterpret_cast<const float4*>(&Wo[(size_t)(n0+r)*HID_ + k0 + c4*4]);
      st4bf(&lB[r*72 + c4*4], vb);
    }
    __syncthreads();
    #pragma unroll
    for (int kc=0;kc<2;kc++){
      bf8 a0 = *reinterpret_cast<const bf8*>(&lA[(wm    + l16)*72 + kc*32 + quad*8]);
      bf8 a1 = *reinterpret_cast<const bf8*>(&lA[(wm+16 + l16)*72 + kc*32 + quad*8]);
      bf8 b0 = *reinterpret_cast<const bf8*>(&lB[(wn    + l16)*72 + kc*32 + quad*8]);
      bf8 b1 = *reinterpret_cast<const bf8*>(&lB[(wn+16 + l16)*72 + kc*32 + quad*8]);
      acc[0][0] = MFMA(a0,b0,acc[0][0]);
      acc[0][1] = MFMA(a0,b1,acc[0][1]);
      acc[1][0] = MFMA(a1,b0,acc[1][0]);
      acc[1][1] = MFMA(a1,b1,acc[1][1]);
    }
    __syncthreads();
  }
  #pragma unroll
  for (int i=0;i<2;i++)
    #pragma unroll
    for (int j=0;j<2;j++)
      #pragma unroll
      for (int reg=0;reg<4;reg++){
        int row = m0 + wm + i*16 + quad*4 + reg;
        int col = n0 + wn + j*16 + l16;
        out[(size_t)row*HID_ + col] = acc[i][j][reg] + bo[col];
      }
}

extern "C" void kernel_launch(void* const* d_in, const int* in_sizes, int n_in,
                              void* d_out, int out_size, void* d_ws, size_t ws_size,
                              hipStream_t stream) {
  const float* key   = (const float*)d_in[0];
  const float* value = (const float*)d_in[1];
  const float* query = (const float*)d_in[2];
  const float* mask  = (const float*)d_in[3];
  const float* pbias = (const float*)d_in[4];
  const float* prev  = (const float*)d_in[5];
  const int*   flag  = (const int*)d_in[6];
  const float* Wq = (const float*)d_in[7];
  const float* bq = (const float*)d_in[8];
  const float* Wk = (const float*)d_in[9];
  const float* bk = (const float*)d_in[10];
  const float* Wv = (const float*)d_in[11];
  const float* bv = (const float*)d_in[12];
  const float* Wo = (const float*)d_in[13];
  const float* bo = (const float*)d_in[14];

  const size_t NQKV = (size_t)B_*H_*S_*D_;        // 3,145,728
  unsigned short* qbuf  = (unsigned short*)d_ws;
  unsigned short* kbuf  = qbuf  + NQKV;
  unsigned short* vtbuf = kbuf  + NQKV;
  unsigned short* ctxb  = vtbuf + NQKV;

  float* out = (float*)d_out;
  float* prev_out = out + (size_t)B_*S_*HID_;     // second tuple output

  proj_kernel<<<dim3(64,12,3), 256, 0, stream>>>(
      query, key, value, Wq, Wk, Wv, bq, bk, bv, qbuf, kbuf, vtbuf);
  attn_kernel<<<dim3(S_/64, H_, B_), 256, 0, stream>>>(
      qbuf, kbuf, vtbuf, pbias, mask, prev, flag, prev_out, ctxb);
  outproj_kernel<<<dim3(64,12), 256, 0, stream>>>(ctxb, Wo, bo, out);
}

// Round 3
// 1130.008 us; speedup vs baseline: 1.6518x; 1.0226x over previous
//
#include <hip/hip_runtime.h>
#include <hip/hip_bf16.h>

#define H_ 12
#define D_ 64
#define S_ 2048
#define B_ 2
#define HID_ 768

typedef short bf8 __attribute__((ext_vector_type(8)));
typedef float f4 __attribute__((ext_vector_type(4)));

#define MFMA(a,b,c) __builtin_amdgcn_mfma_f32_16x16x32_bf16(a,b,c,0,0,0)

__device__ __forceinline__ unsigned short f2bf(float f){
  __hip_bfloat16 h = __float2bfloat16(f);
  return __builtin_bit_cast(unsigned short, h);
}

__device__ __forceinline__ void st4bf(unsigned short* dst, float4 v){
  unsigned int u0 = (unsigned int)f2bf(v.x) | ((unsigned int)f2bf(v.y) << 16);
  unsigned int u1 = (unsigned int)f2bf(v.z) | ((unsigned int)f2bf(v.w) << 16);
  uint2 u; u.x = u0; u.y = u1;
  *reinterpret_cast<uint2*>(dst) = u;
}

// ---------------- QKV projection: y = x @ W^T + b, routed to bf16 buffers ----
// q,k -> [B,H,S,D]; v -> transposed [B,H,D,S]
__global__ __launch_bounds__(256) void proj_kernel(
    const float* __restrict__ Xq, const float* __restrict__ Xk, const float* __restrict__ Xv,
    const float* __restrict__ Wq_, const float* __restrict__ Wk_, const float* __restrict__ Wv_,
    const float* __restrict__ bq_, const float* __restrict__ bk_, const float* __restrict__ bv_,
    unsigned short* __restrict__ qb, unsigned short* __restrict__ kb,
    unsigned short* __restrict__ vtb)
{
  const int sel = blockIdx.z;
  const float* X    = sel==0 ? Xq  : (sel==1 ? Xk  : Xv);
  const float* W    = sel==0 ? Wq_ : (sel==1 ? Wk_ : Wv_);
  const float* bias = sel==0 ? bq_ : (sel==1 ? bk_ : bv_);
  const int m0 = blockIdx.x*64, n0 = blockIdx.y*64;
  __shared__ unsigned short lA[64*72];  // +8 pad: bank-friendly, keeps 16B align
  __shared__ unsigned short lB[64*72];
  const int tid = threadIdx.x;
  const int lane = tid & 63, w = tid >> 6;
  const int quad = lane >> 4, l16 = lane & 15;
  const int wm = (w>>1)*32, wn = (w&1)*32;
  f4 acc[2][2] = {};
  for (int k0=0; k0<HID_; k0+=64){
    #pragma unroll
    for (int i=0;i<4;i++){
      int idx = tid + i*256;               // 0..1023
      int r = idx>>4, c4 = idx&15;         // 64 rows x 16 float4
      float4 va = *reinterpret_cast<const float4*>(&X[(size_t)(m0+r)*HID_ + k0 + c4*4]);
      st4bf(&lA[r*72 + c4*4], va);
      float4 vb = *reinterpret_cast<const float4*>(&W[(size_t)(n0+r)*HID_ + k0 + c4*4]);
      st4bf(&lB[r*72 + c4*4], vb);
    }
    __syncthreads();
    #pragma unroll
    for (int kc=0;kc<2;kc++){
      bf8 a0 = *reinterpret_cast<const bf8*>(&lA[(wm    + l16)*72 + kc*32 + quad*8]);
      bf8 a1 = *reinterpret_cast<const bf8*>(&lA[(wm+16 + l16)*72 + kc*32 + quad*8]);
      bf8 b0 = *reinterpret_cast<const bf8*>(&lB[(wn    + l16)*72 + kc*32 + quad*8]);
      bf8 b1 = *reinterpret_cast<const bf8*>(&lB[(wn+16 + l16)*72 + kc*32 + quad*8]);
      acc[0][0] = MFMA(a0,b0,acc[0][0]);
      acc[0][1] = MFMA(a0,b1,acc[0][1]);
      acc[1][0] = MFMA(a1,b0,acc[1][0]);
      acc[1][1] = MFMA(a1,b1,acc[1][1]);
    }
    __syncthreads();
  }
  #pragma unroll
  for (int i=0;i<2;i++)
    #pragma unroll
    for (int j=0;j<2;j++)
      #pragma unroll
      for (int reg=0;reg<4;reg++){
        int row = m0 + wm + i*16 + quad*4 + reg;     // b*S+s
        int col = n0 + wn + j*16 + l16;              // h*64+d
        float val = acc[i][j][reg] + bias[col];
        int bb = row >> 11, s = row & 2047;
        int hh = col >> 6,  d = col & 63;
        unsigned short bv16 = f2bf(val);
        if (sel==0)      qb [((size_t)(bb*H_+hh)*S_ + s)*D_ + d] = bv16;
        else if (sel==1) kb [((size_t)(bb*H_+hh)*S_ + s)*D_ + d] = bv16;
        else             vtb[((size_t)(bb*H_+hh)*D_ + d)*S_ + s] = bv16;
      }
}

// ---------------- fused attention: scores + prev_attn_out + online softmax + PV
// Swapped-operand QK^T (scores transposed per lane). This revision:
//  (1) XCD-aware block swizzle: each XCD owns 3 whole (b,h) groups -> K/V L2-resident.
//  (2) Batched load issue per tile: all K frags, then all pb/mk, THEN QK MFMAs
//      (counted vmcnt lets 16 fp32 loads fly under the MFMAs), pv next, and all
//      16 V fragments hoisted ahead of the PV MFMA cluster. Raises per-wave
//      outstanding bytes (Little's law) on a grid-limited-occupancy kernel.
__global__ __launch_bounds__(256) void attn_kernel(
  const unsigned short* __restrict__ qb, const unsigned short* __restrict__ kb,
  const unsigned short* __restrict__ vtb,
  const float* __restrict__ pb, const float* __restrict__ msk,
  const float* __restrict__ prev, const int* __restrict__ flagp,
  float* __restrict__ prev_out, unsigned short* __restrict__ ctxb)
{
  // bijective XCD swizzle over the 768-block grid (768%8==0)
  const int lin = blockIdx.x + 32*blockIdx.y + 384*blockIdx.z;  // qt fastest
  const int wg  = (lin & 7)*96 + (lin >> 3);
  const int qt  = wg & 31;
  const int hb  = wg >> 5;            // 0..23 = head-batch group
  const int bb  = (hb >= H_) ? 1 : 0;
  const int hh  = hb - bb*H_;
  const int tid = threadIdx.x, w = tid>>6, lane = tid&63;
  const int quad = lane>>4, l16 = lane&15;
  const int flag = *flagp;
  __shared__ unsigned short lP[4*16*136];   // per-wave [16 q][128 k] strips, pad 136
  const int pbase = w*16*136;
  const unsigned short* Kb = kb  + (size_t)(bb*H_+hh)*S_*D_;
  const unsigned short* Vb = vtb + (size_t)(bb*H_+hh)*D_*S_;
  const unsigned short* Qb = qb  + (size_t)(bb*H_+hh)*S_*D_;
  const int q0 = qt*64;
  const int qq = q0 + w*16 + l16;           // this lane's q row
  bf8 qf0 = *reinterpret_cast<const bf8*>(&Qb[(size_t)qq*D_ + quad*8]);
  bf8 qf1 = *reinterpret_cast<const bf8*>(&Qb[(size_t)qq*D_ + 32 + quad*8]);
  const float* pbB = pb   + (size_t)hh*S_*S_;
  const float* mkB = msk  + (size_t)bb*S_*S_;
  const float* pvB = prev + (size_t)(bb*H_+hh)*S_*S_;
  float*       poB = prev_out + (size_t)(bb*H_+hh)*S_*S_;

  float m_run = -1e30f, l_run = 0.f;
  f4 O[4] = {};                             // O^T: d = n*16+quad*4+reg, q = l16

  for (int kt=0; kt<S_; kt+=128){
    // ---- phase 1: issue all K fragment loads (head of dependency chain)
    bf8 kv0[8], kv1[8];
    #pragma unroll
    for (int c=0;c<8;c++){
      const unsigned short* kr = &Kb[(size_t)(kt + c*16 + l16)*D_ + quad*8];
      kv0[c] = *reinterpret_cast<const bf8*>(kr);
      kv1[c] = *reinterpret_cast<const bf8*>(kr + 32);
    }
    // ---- phase 2: issue pb/mk loads (fly under the QK MFMAs)
    f4 pbv[8], mkv[8];
    #pragma unroll
    for (int c=0;c<8;c++){
      size_t off = (size_t)qq*S_ + kt + c*16 + quad*4;
      pbv[c] = *reinterpret_cast<const f4*>(&pbB[off]);
      mkv[c] = *reinterpret_cast<const f4*>(&mkB[off]);
    }
    // ---- phase 3: QK^T (waits only on K via counted vmcnt)
    f4 sc[8];
    #pragma unroll
    for (int c=0;c<8;c++){
      f4 z = {};
      z = MFMA(kv0[c], qf0, z);
      z = MFMA(kv1[c], qf1, z);
      sc[c] = z;
    }
    // ---- phase 4: issue prev loads
    f4 pvv[8];
    if (flag){
      #pragma unroll
      for (int c=0;c<8;c++){
        size_t off = (size_t)qq*S_ + kt + c*16 + quad*4;
        pvv[c] = *reinterpret_cast<const f4*>(&pvB[off]);
      }
    } else {
      #pragma unroll
      for (int c=0;c<8;c++){ pvv[c][0]=0.f; pvv[c][1]=0.f; pvv[c][2]=0.f; pvv[c][3]=0.f; }
    }
    // ---- phase 5: partial assemble (frees pb/mk)
    #pragma unroll
    for (int c=0;c<8;c++)
      #pragma unroll
      for (int reg=0;reg<4;reg++)
        sc[c][reg] = (sc[c][reg] + pbv[c][reg])*0.125f + mkv[c][reg];
    // ---- phase 6: + prev, prev_out store, running max
    float mt = -1e30f;
    #pragma unroll
    for (int c=0;c<8;c++){
      size_t off = (size_t)qq*S_ + kt + c*16 + quad*4;
      f4 vout;
      #pragma unroll
      for (int reg=0;reg<4;reg++){
        float v = sc[c][reg] + pvv[c][reg];
        vout[reg] = v;
        mt = fmaxf(mt, v);
      }
      *reinterpret_cast<f4*>(&poB[off]) = vout;
      sc[c] = vout;
    }
    // ---- phase 7: issue all V fragment loads (fly under softmax + P-write)
    bf8 vvr[4][4];
    #pragma unroll
    for (int kb_=0;kb_<4;kb_++)
      #pragma unroll
      for (int n=0;n<4;n++)
        vvr[kb_][n] = *reinterpret_cast<const bf8*>(
            &Vb[(size_t)(n*16+l16)*S_ + kt + kb_*32 + quad*8]);
    // ---- phase 8: online softmax (per-lane scalar state, cross-quad reduce)
    mt = fmaxf(mt, __shfl_xor(mt, 16, 64));
    mt = fmaxf(mt, __shfl_xor(mt, 32, 64));
    float mn = fmaxf(m_run, mt);
    float al = __expf(m_run - mn);
    m_run = mn;
    float ps = 0.f;
    #pragma unroll
    for (int c=0;c<8;c++)
      #pragma unroll
      for (int reg=0;reg<4;reg++){
        float p = __expf(sc[c][reg] - mn);
        sc[c][reg] = p;
        ps += p;
      }
    ps += __shfl_xor(ps, 16, 64);
    ps += __shfl_xor(ps, 32, 64);
    l_run = l_run*al + ps;
    #pragma unroll
    for (int n=0;n<4;n++)
      #pragma unroll
      for (int reg=0;reg<4;reg++) O[n][reg] *= al;
    // ---- phase 9: P -> per-wave LDS strip, 8B packed stores
    #pragma unroll
    for (int c=0;c<8;c++){
      unsigned int u0 = (unsigned int)f2bf(sc[c][0]) | ((unsigned int)f2bf(sc[c][1])<<16);
      unsigned int u1 = (unsigned int)f2bf(sc[c][2]) | ((unsigned int)f2bf(sc[c][3])<<16);
      uint2 u; u.x=u0; u.y=u1;
      *reinterpret_cast<uint2*>(&lP[pbase + l16*136 + c*16 + quad*4]) = u;
    }
    // ---- phase 10: O^T += Vt P^T (V already in regs)
    #pragma unroll
    for (int kb_=0;kb_<4;kb_++){
      bf8 pa = *reinterpret_cast<const bf8*>(&lP[pbase + l16*136 + kb_*32 + quad*8]);
      #pragma unroll
      for (int n=0;n<4;n++)
        O[n] = MFMA(vvr[kb_][n], pa, O[n]);
    }
  }
  // epilogue: ctx = O^T / l, store bf16 [B,S,H*D]; 4 contiguous d per n -> 8B stores
  float rcp = 1.f / l_run;
  #pragma unroll
  for (int n=0;n<4;n++){
    unsigned int u0 = (unsigned int)f2bf(O[n][0]*rcp) | ((unsigned int)f2bf(O[n][1]*rcp)<<16);
    unsigned int u1 = (unsigned int)f2bf(O[n][2]*rcp) | ((unsigned int)f2bf(O[n][3]*rcp)<<16);
    uint2 u; u.x=u0; u.y=u1;
    *reinterpret_cast<uint2*>(&ctxb[(size_t)(bb*S_+qq)*HID_ + hh*D_ + n*16 + quad*4]) = u;
  }
}

// ---------------- output projection: out = ctx @ Wo^T + bo (fp32 out) --------
__global__ __launch_bounds__(256) void outproj_kernel(
  const unsigned short* __restrict__ ctxb, const float* __restrict__ Wo,
  const float* __restrict__ bo, float* __restrict__ out)
{
  const int m0 = blockIdx.x*64, n0 = blockIdx.y*64;
  __shared__ unsigned short lA[64*72];
  __shared__ unsigned short lB[64*72];
  const int tid = threadIdx.x;
  const int lane = tid&63, w = tid>>6;
  const int quad = lane>>4, l16 = lane&15;
  const int wm = (w>>1)*32, wn = (w&1)*32;
  f4 acc[2][2] = {};
  for (int k0=0;k0<HID_;k0+=64){
    #pragma unroll
    for (int i=0;i<2;i++){
      int idx = tid + i*256;                // 0..511
      int r = idx>>3, c8 = idx&7;
      *reinterpret_cast<uint4*>(&lA[r*72 + c8*8]) =
        *reinterpret_cast<const uint4*>(&ctxb[(size_t)(m0+r)*HID_ + k0 + c8*8]);
    }
    #pragma unroll
    for (int i=0;i<4;i++){
      int idx = tid + i*256;
      int r = idx>>4, c4 = idx&15;
      float4 vb = *reinterpret_cast<const float4*>(&Wo[(size_t)(n0+r)*HID_ + k0 + c4*4]);
      st4bf(&lB[r*72 + c4*4], vb);
    }
    __syncthreads();
    #pragma unroll
    for (int kc=0;kc<2;kc++){
      bf8 a0 = *reinterpret_cast<const bf8*>(&lA[(wm    + l16)*72 + kc*32 + quad*8]);
      bf8 a1 = *reinterpret_cast<const bf8*>(&lA[(wm+16 + l16)*72 + kc*32 + quad*8]);
      bf8 b0 = *reinterpret_cast<const bf8*>(&lB[(wn    + l16)*72 + kc*32 + quad*8]);
      bf8 b1 = *reinterpret_cast<const bf8*>(&lB[(wn+16 + l16)*72 + kc*32 + quad*8]);
      acc[0][0] = MFMA(a0,b0,acc[0][0]);
      acc[0][1] = MFMA(a0,b1,acc[0][1]);
      acc[1][0] = MFMA(a1,b0,acc[1][0]);
      acc[1][1] = MFMA(a1,b1,acc[1][1]);
    }
    __syncthreads();
  }
  #pragma unroll
  for (int i=0;i<2;i++)
    #pragma unroll
    for (int j=0;j<2;j++)
      #pragma unroll
      for (int reg=0;reg<4;reg++){
        int row = m0 + wm + i*16 + quad*4 + reg;
        int col = n0 + wn + j*16 + l16;
        out[(size_t)row*HID_ + col] = acc[i][j][reg] + bo[col];
      }
}

extern "C" void kernel_launch(void* const* d_in, const int* in_sizes, int n_in,
                              void* d_out, int out_size, void* d_ws, size_t ws_size,
                              hipStream_t stream) {
  const float* key   = (const float*)d_in[0];
  const float* value = (const float*)d_in[1];
  const float* query = (const float*)d_in[2];
  const float* mask  = (const float*)d_in[3];
  const float* pbias = (const float*)d_in[4];
  const float* prev  = (const float*)d_in[5];
  const int*   flag  = (const int*)d_in[6];
  const float* Wq = (const float*)d_in[7];
  const float* bq = (const float*)d_in[8];
  const float* Wk = (const float*)d_in[9];
  const float* bk = (const float*)d_in[10];
  const float* Wv = (const float*)d_in[11];
  const float* bv = (const float*)d_in[12];
  const float* Wo = (const float*)d_in[13];
  const float* bo = (const float*)d_in[14];

  const size_t NQKV = (size_t)B_*H_*S_*D_;        // 3,145,728
  unsigned short* qbuf  = (unsigned short*)d_ws;
  unsigned short* kbuf  = qbuf  + NQKV;
  unsigned short* vtbuf = kbuf  + NQKV;
  unsigned short* ctxb  = vtbuf + NQKV;

  float* out = (float*)d_out;
  float* prev_out = out + (size_t)B_*S_*HID_;     // second tuple output

  proj_kernel<<<dim3(64,12,3), 256, 0, stream>>>(
      query, key, value, Wq, Wk, Wv, bq, bk, bv, qbuf, kbuf, vtbuf);
  attn_kernel<<<dim3(S_/64, H_, B_), 256, 0, stream>>>(
      qbuf, kbuf, vtbuf, pbias, mask, prev, flag, prev_out, ctxb);
  outproj_kernel<<<dim3(64,12), 256, 0, stream>>>(ctxb, Wo, bo, out);
}